// Round 3
// baseline (518.004 us; speedup 1.0000x reference)
//
#include <hip/hip_runtime.h>

// QAttentionLayer: out[..., i] = prod_{j<=i} cos(x_j)*cos(w_j), rows of 10 fp32.
// Memory-bound streaming (335 MB kernel traffic -> ~53 us kernel floor).
//
// R3b: NO-LDS variant (decisive experiment), compile-fixed: nontemporal
// builtins need a clang ext_vector type, not HIP_vector_type<float,4>.
//
// Rationale (from R0==R2 null): LDS path was never critical; remaining suspect
// for a >floor kernel is the block-wide vmcnt(0)+s_barrier drain, 2x/block.
// A row-PAIR is 80 B = 5 aligned 16B vectors, so each thread owns one pair
// directly from global: no LDS, no barriers, copy-like independent dataflow.
// The 5 load instrs per lane jointly cover a contiguous 5 KB/wave span; L1
// MSHRs merge same-line requests -> HBM traffic unchanged at 2x167.8 MB.
// Nontemporal hints: pure streaming, 335 MB >> 32 MB L2.
//
// Predicted: if barrier-drain was real, bench 283 -> ~258-265; if unchanged,
// kernel is at the traffic floor and the bench is harness-fill-dominated.

#define BLOCK 256
#define NQ 10

typedef float f32x4 __attribute__((ext_vector_type(4)));

__global__ __launch_bounds__(BLOCK) void qcircuit_kernel(
    const float* __restrict__ x,
    const float* __restrict__ w,
    float* __restrict__ out,
    long long n_rows)
{
    const long long n_pairs = n_rows >> 1;
    const long long p = (long long)blockIdx.x * BLOCK + threadIdx.x;

    // cos(weights): uniform scalar loads (s_load), 10 v_cos per thread
    float cw[NQ];
    #pragma unroll
    for (int j = 0; j < NQ; ++j) cw[j] = __cosf(w[j]);

    if (p < n_pairs) {
        const f32x4* __restrict__ gin  = (const f32x4*)x   + p * 5;
        f32x4* __restrict__       gout = (f32x4*)out       + p * 5;

        float v[20];                         // static indexing -> stays in VGPRs
        f32x4* vr = (f32x4*)v;
        #pragma unroll
        for (int k = 0; k < 5; ++k) vr[k] = __builtin_nontemporal_load(gin + k);

        float pr = 1.0f;
        #pragma unroll
        for (int j = 0; j < NQ; ++j) { pr *= __cosf(v[j]) * cw[j]; v[j] = pr; }
        pr = 1.0f;
        #pragma unroll
        for (int j = 0; j < NQ; ++j) { pr *= __cosf(v[NQ + j]) * cw[j]; v[NQ + j] = pr; }

        #pragma unroll
        for (int k = 0; k < 5; ++k) __builtin_nontemporal_store(vr[k], gout + k);
    } else if ((n_rows & 1) && p == n_pairs) {
        // odd tail row (not hit at bench shape): scalar in-place
        const float* gi = x   + 2 * n_pairs * NQ;
        float*       go = out + 2 * n_pairs * NQ;
        float pr = 1.0f;
        #pragma unroll
        for (int j = 0; j < NQ; ++j) { pr *= __cosf(gi[j]) * cw[j]; go[j] = pr; }
    }
}

extern "C" void kernel_launch(void* const* d_in, const int* in_sizes, int n_in,
                              void* d_out, int out_size, void* d_ws, size_t ws_size,
                              hipStream_t stream) {
    const float* x = (const float*)d_in[0];
    const float* w = (const float*)d_in[1];
    float* out = (float*)d_out;

    const long long n_elem = in_sizes[0];
    const long long n_rows = n_elem / NQ;
    const long long n_work = (n_rows >> 1) + (n_rows & 1);   // pairs + tail row
    const int blocks = (int)((n_work + BLOCK - 1) / BLOCK);

    hipLaunchKernelGGL(qcircuit_kernel, dim3(blocks), dim3(BLOCK), 0, stream,
                       x, w, out, n_rows);
}

// Round 4
// 287.466 us; speedup vs baseline: 1.8020x; 1.8020x over previous
//
#include <hip/hip_runtime.h>

// QAttentionLayer: out[..., i] = prod_{j<=i} cos(x_j)*cos(w_j), rows of 10 fp32.
// Memory-bound streaming: 335.5 MB kernel traffic -> 53 us kernel floor.
//
// Known facts: bench = ~201 us harness fills (immovable) + kernel.
//   R0/R2 (single-tile-per-block LDS stage): kernel ~82 us = 4.1 TB/s.
//   R3b (no-LDS, 80B-stride nt stores): 313 us, WRITE_SIZE 3.4x ideal ->
//   partial-line writes. Coalesced LDS transpose is mandatory.
//
// R4: double-buffered persistent pipeline (T3/T4-lite). R0==R2 showed
// intra-phase detail is irrelevant; the shared flaw is zero load-latency
// cover (loads -> immediate vmcnt(0)+barrier drain, the m97 stall class).
// Here each block walks 8 tiles; tile t+1's global_load_lds DMA is issued
// before compute/store of tile t, and the only waits are counted vmcnt(5)
// + raw s_barrier (never vmcnt(0) in the loop).
//
// vmcnt bookkeeping (per thread, all waves uniform -- no guarded skips in
// full tiles): issue order is ... L_{t+1}(5 gll), S_t(5 stores).
// At bottom-of-iter, vmcnt(5) leaves <=5 outstanding; in-order retirement
// (m135) => the 5 newest are S_t, so L_{t+1} has landed. Barrier then
// separates this iter's LDS reads from next iter's DMA overwrite.
//
// Predicted: kernel 82 -> ~58-65 us, bench 283 -> ~260-268. If unchanged,
// the limiter is the mixed R/W stream itself, not latency exposure.

#define BLOCK 256
#define NQ 10
#define TILE_U4 1280                 // 512 rows = 5120 fp32 = 20 KiB
#define U4T 5                        // TILE_U4 / BLOCK
#define GRID 1024                    // 2 bufs * 20 KiB = 40 KiB -> 4 blocks/CU, all resident

typedef float f32x4 __attribute__((ext_vector_type(4)));

__global__ __launch_bounds__(BLOCK) void qcircuit_kernel(
    const float* __restrict__ x,
    const float* __restrict__ w,
    float* __restrict__ out,
    long long n_rows)
{
    __shared__ f32x4 bufA[TILE_U4];
    __shared__ f32x4 bufB[TILE_U4];

    const int tid = threadIdx.x;
    const long long total_u4 = ((long long)n_rows * NQ) / 4;
    const long long ntiles   = total_u4 / TILE_U4;       // full tiles only
    const f32x4* __restrict__ gin  = (const f32x4*)x;
    f32x4* __restrict__       gout = (f32x4*)out;

    float cw[NQ];
    #pragma unroll
    for (int j = 0; j < NQ; ++j) cw[j] = __cosf(w[j]);

#define STAGE(dst, t)                                                          \
    _Pragma("unroll")                                                          \
    for (int k = 0; k < U4T; ++k) {                                            \
        __builtin_amdgcn_global_load_lds(                                      \
            (const __attribute__((address_space(1))) void*)                    \
                (gin + (t) * TILE_U4 + k * BLOCK + tid),                       \
            (__attribute__((address_space(3))) void*)((dst) + k * BLOCK + tid),\
            16, 0, 0);                                                         \
    }

    const long long t0 = blockIdx.x;
    if (t0 < ntiles) { STAGE(bufA, t0); }

    // prologue drain (the only vmcnt(0) in the kernel)
    asm volatile("s_waitcnt vmcnt(0)" ::: "memory");
    __builtin_amdgcn_s_barrier();

    long long i = 0;
    for (long long t = t0; t < ntiles; t += GRID, ++i) {
        f32x4* cur = (i & 1) ? bufB : bufA;
        f32x4* nxt = (i & 1) ? bufA : bufB;
        const bool have_next = (t + GRID) < ntiles;

        // ---- issue next tile's DMA first: a full compute+store phase of cover
        if (have_next) { STAGE(nxt, t + GRID); }

        // ---- compute phase: one row-pair per thread, in-place in LDS
        {
            float v[20];                          // static indexing -> VGPRs
            f32x4* vr = (f32x4*)v;
            #pragma unroll
            for (int k = 0; k < U4T; ++k) vr[k] = cur[tid * U4T + k];

            float pr = 1.0f;
            #pragma unroll
            for (int j = 0; j < NQ; ++j) { pr *= __cosf(v[j]) * cw[j]; v[j] = pr; }
            pr = 1.0f;
            #pragma unroll
            for (int j = 0; j < NQ; ++j) { pr *= __cosf(v[NQ + j]) * cw[j]; v[NQ + j] = pr; }

            #pragma unroll
            for (int k = 0; k < U4T; ++k) cur[tid * U4T + k] = vr[k];
        }

        // ds_writes visible block-wide before the transposed store-phase reads
        asm volatile("s_waitcnt lgkmcnt(0)" ::: "memory");
        __builtin_amdgcn_s_barrier();

        // ---- coalesced store phase (full 64B lines per 4 lanes -> nt is safe)
        #pragma unroll
        for (int k = 0; k < U4T; ++k) {
            f32x4 sv = cur[k * BLOCK + tid];      // ds_read_b128, compiler waits lgkm
            __builtin_nontemporal_store(sv, gout + t * TILE_U4 + k * BLOCK + tid);
        }

        // next tile's loads landed (see header comment); never drain stores
        if (have_next) { asm volatile("s_waitcnt vmcnt(5)" ::: "memory"); }
        __builtin_amdgcn_s_barrier();             // protect cur from next DMA overwrite
    }

    // ---- generic tail (rows beyond full tiles): barrier-free scalar path.
    // Not hit at bench shape (8192 tiles exactly).
    if (blockIdx.x == 0) {
        for (long long r = ntiles * (TILE_U4 * 4 / NQ) + tid; r < n_rows; r += BLOCK) {
            const float* gi = x   + r * NQ;
            float*       go = out + r * NQ;
            float pr = 1.0f;
            #pragma unroll
            for (int j = 0; j < NQ; ++j) { pr *= __cosf(gi[j]) * cw[j]; go[j] = pr; }
        }
    }
#undef STAGE
}

extern "C" void kernel_launch(void* const* d_in, const int* in_sizes, int n_in,
                              void* d_out, int out_size, void* d_ws, size_t ws_size,
                              hipStream_t stream) {
    const float* x = (const float*)d_in[0];
    const float* w = (const float*)d_in[1];
    float* out = (float*)d_out;

    const long long n_elem = in_sizes[0];
    const long long n_rows = n_elem / NQ;
    const long long total_u4 = (n_rows * NQ) / 4;
    const long long ntiles = total_u4 / TILE_U4;
    long long blocks = ntiles < GRID ? ntiles : GRID;
    if (blocks < 1) blocks = 1;                  // tail-only degenerate case

    hipLaunchKernelGGL(qcircuit_kernel, dim3((int)blocks), dim3(BLOCK), 0, stream,
                       x, w, out, n_rows);
}

// Round 5
// 281.629 us; speedup vs baseline: 1.8393x; 1.0207x over previous
//
#include <hip/hip_runtime.h>

// QAttentionLayer: out[..., i] = prod_{j<=i} cos(x_j)*cos(w_j), rows of 10 fp32.
// Memory-bound streaming: 335.5 MB kernel traffic; floor 40-53 us (L3 absorbs
// part of the fetch: R4 profile showed FETCH=80MB effective).
//
// Ledger: bench = ~186.5 us harness fills + kernel.
//   R0/R2 (block-tile LDS, vmcnt(0)+2 barriers/tile): kernel ~96 us, 3.5 TB/s
//   R4 (dbuf pipeline, 40KiB LDS -> 16 waves/CU, nt stores): 101 us. Occupancy
//       traded for ILP = net loss; counted-vmcnt also coupled to nt-store drain.
//   R3b (no LDS, 80B lane stride): WRITE_SIZE 3.4x -> partial-line writes.
//
// R5: WAVE-AUTONOMOUS, ZERO-BARRIER version of R2. The linear<->row-pair
// transpose only spans 320 f32x4 = one wave's 5 KiB chunk, so no cross-wave
// data flows: each wave stages its chunk (5x global_load_lds, 1 KiB/pass
// coalesced), waits its OWN vmcnt(0), computes row-pairs in-place, waits its
// OWN lgkmcnt(0), and stores linearly. No s_barrier anywhere -> no block-wide
// convoy on the slowest wave's HBM latency. LDS stays 20 KiB/block ->
// 8 blocks/CU -> 32 waves/CU (R4's mistake undone). Structurally = m13 copy
// (independent per-wave load->store chains, TLP-hidden) + LDS detour.
// Wave-sync correctness: all cross-lane LDS traffic is within one wave,
// ordered by the wave's own lgkmcnt(0) drains (lockstep issue).
//
// Predicted: kernel 96 -> 60-70 us, bench 283 -> ~255-268. If unchanged,
// barriers exonerated -> limiter is the DMA chain / mixed R+W stream itself.

#define BLOCK 256
#define WAVES 4
#define NQ 10
#define WQ 320                    // f32x4 per wave-tile = 5 KiB = 128 rows
#define ROWS_PER_WAVE 128

typedef float f32x4 __attribute__((ext_vector_type(4)));

__global__ __launch_bounds__(BLOCK) void qcircuit_kernel(
    const float* __restrict__ x,
    const float* __restrict__ w,
    float* __restrict__ out,
    long long n_rows,
    long long nfull)              // number of full 128-row wave-tiles
{
    __shared__ f32x4 buf[WAVES * WQ];   // 20 KiB -> 8 blocks/CU

    const int tid  = threadIdx.x;
    const int wid  = tid >> 6;
    const int lane = tid & 63;
    f32x4* wbuf = buf + wid * WQ;

    const f32x4* __restrict__ gin  = (const f32x4*)x;
    f32x4* __restrict__       gout = (f32x4*)out;

    // cos(weights): uniform scalar loads
    float cw[NQ];
    #pragma unroll
    for (int j = 0; j < NQ; ++j) cw[j] = __cosf(w[j]);

    const long long wtile = (long long)blockIdx.x * WAVES + wid;

    if (wtile < nfull) {
        const long long base_u4 = wtile * WQ;

        // ---- stage: 5 passes, each 64 lanes x 16 B = 1 KiB contiguous ----
        #pragma unroll
        for (int p = 0; p < 5; ++p) {
            __builtin_amdgcn_global_load_lds(
                (const __attribute__((address_space(1))) void*)
                    (gin + base_u4 + p * 64 + lane),
                (__attribute__((address_space(3))) void*)(wbuf + p * 64 + lane),
                16, 0, 0);
        }
        asm volatile("s_waitcnt vmcnt(0)" ::: "memory");   // this wave's DMA only
        __builtin_amdgcn_sched_barrier(0);

        // ---- compute: lane owns row-pair 'lane' = f32x4 [5*lane .. 5*lane+4]
        float v[20];                       // static indexing -> stays in VGPRs
        f32x4* vr = (f32x4*)v;
        #pragma unroll
        for (int k = 0; k < 5; ++k) vr[k] = wbuf[lane * 5 + k];

        float pr = 1.0f;
        #pragma unroll
        for (int j = 0; j < NQ; ++j) { pr *= __cosf(v[j]) * cw[j]; v[j] = pr; }
        pr = 1.0f;
        #pragma unroll
        for (int j = 0; j < NQ; ++j) { pr *= __cosf(v[NQ + j]) * cw[j]; v[NQ + j] = pr; }

        #pragma unroll
        for (int k = 0; k < 5; ++k) wbuf[lane * 5 + k] = vr[k];

        asm volatile("s_waitcnt lgkmcnt(0)" ::: "memory"); // this wave's ds_writes
        __builtin_amdgcn_sched_barrier(0);

        // ---- store: linear re-read, 1 KiB contiguous per pass ----
        #pragma unroll
        for (int p = 0; p < 5; ++p) {
            f32x4 sv = wbuf[p * 64 + lane];
            gout[base_u4 + p * 64 + lane] = sv;
        }
    }

    // ---- generic tail (rows beyond full wave-tiles): scalar, never at bench
    // shape (4,194,304 rows = 32768 x 128 exactly). Barrier-free.
    if (blockIdx.x == 0 && wid == 0) {
        for (long long r = nfull * ROWS_PER_WAVE + lane; r < n_rows; r += 64) {
            const float* gi = x   + r * NQ;
            float*       go = out + r * NQ;
            float pr = 1.0f;
            #pragma unroll
            for (int j = 0; j < NQ; ++j) { pr *= __cosf(gi[j]) * cw[j]; go[j] = pr; }
        }
    }
}

extern "C" void kernel_launch(void* const* d_in, const int* in_sizes, int n_in,
                              void* d_out, int out_size, void* d_ws, size_t ws_size,
                              hipStream_t stream) {
    const float* x = (const float*)d_in[0];
    const float* w = (const float*)d_in[1];
    float* out = (float*)d_out;

    const long long n_elem = in_sizes[0];
    const long long n_rows = n_elem / NQ;
    const long long total_u4 = (n_rows * NQ) / 4;
    const long long nfull = total_u4 / WQ;                 // full 128-row wave-tiles
    long long blocks = (nfull + WAVES - 1) / WAVES;
    if (blocks < 1) blocks = 1;                            // tail-only degenerate case

    hipLaunchKernelGGL(qcircuit_kernel, dim3((int)blocks), dim3(BLOCK), 0, stream,
                       x, w, out, n_rows, nfull);
}